// Round 3
// baseline (764.206 us; speedup 1.0000x reference)
//
#include <hip/hip_runtime.h>

// GCN 2-layer forward for MI355X.
// NOTE: edge_index is uploaded by the harness as int32 (harness converts all
// integer inputs to int) — round-2 crash was casting it to long long.
// Pipeline:
//  1. memset deg=0
//  2. k_hist: deg[dst]++ over edges (int atomics)
//  3. k_scan1/2/3: exclusive scan of deg -> rowptr (CSR), cursor=rowptr, dinv=rsqrt(deg+1)
//  4. k_fill: CSR column fill via atomic cursor
//  5. k_gemm1: h1s = (X @ W1) * dinv[row]      (f32, 128x128x32 LDS tile, k-major A)
//  6. k_agg1:  hrelu = relu(dinv*(sum h1s[src] + h1s[self]) + b1)   (wave per node)
//  7. k_gemm2: h2s = (hrelu @ W2) * dinv[row]  (W2 fully in LDS)
//  8. k_agg2:  out = dinv*(sum h2s[src] + h2s[self]) + b2

#define NFEAT 256
#define HID   128
#define NCLS  40

// ---------------- histogram ----------------
__global__ void k_hist(const int* __restrict__ dst, int* __restrict__ deg, int E) {
    int stride = gridDim.x * blockDim.x;
    for (int e = blockIdx.x * blockDim.x + threadIdx.x; e < E; e += stride)
        atomicAdd(&deg[dst[e]], 1);
}

// ---------------- scan (1024 elems / block) ----------------
__global__ void k_scan1(const int* __restrict__ deg, int* __restrict__ rowptr,
                        int* __restrict__ blockSums, float* __restrict__ dinv, int N) {
    __shared__ int sums[256];
    int t = threadIdx.x;
    int base = blockIdx.x * 1024 + t * 4;
    int c[4];
#pragma unroll
    for (int j = 0; j < 4; j++) {
        int idx = base + j;
        c[j] = (idx < N) ? deg[idx] : 0;
        if (idx < N) dinv[idx] = rsqrtf((float)(c[j] + 1));
    }
    int s = c[0] + c[1] + c[2] + c[3];
    sums[t] = s;
    __syncthreads();
    for (int off = 1; off < 256; off <<= 1) {
        int v = (t >= off) ? sums[t - off] : 0;
        __syncthreads();
        sums[t] += v;
        __syncthreads();
    }
    int run = sums[t] - s;  // exclusive prefix of this thread's 4
#pragma unroll
    for (int j = 0; j < 4; j++) {
        int idx = base + j;
        if (idx < N) rowptr[idx] = run;
        run += c[j];
    }
    if (t == 255) blockSums[blockIdx.x] = sums[255];
}

__global__ void k_scan2(int* __restrict__ blockSums, int* __restrict__ rowptr,
                        int nblocks, int N) {
    __shared__ int sh[128];
    int t = threadIdx.x;  // blockDim = 128, nblocks <= 128
    int v = (t < nblocks) ? blockSums[t] : 0;
    sh[t] = v;
    __syncthreads();
    for (int off = 1; off < 128; off <<= 1) {
        int u = (t >= off) ? sh[t - off] : 0;
        __syncthreads();
        sh[t] += u;
        __syncthreads();
    }
    blockSums[t] = sh[t] - v;          // exclusive
    if (t == 127) rowptr[N] = sh[127]; // total = E
}

__global__ void k_scan3(int* __restrict__ rowptr, const int* __restrict__ blockSums,
                        int* __restrict__ cursor, int N) {
    int stride = gridDim.x * blockDim.x;
    for (int i = blockIdx.x * blockDim.x + threadIdx.x; i < N; i += stride) {
        int v = rowptr[i] + blockSums[i >> 10];
        rowptr[i] = v;
        cursor[i] = v;
    }
}

// ---------------- CSR fill ----------------
__global__ void k_fill(const int* __restrict__ src, const int* __restrict__ dst,
                       int* __restrict__ cursor, int* __restrict__ col, int E) {
    int stride = gridDim.x * blockDim.x;
    for (int e = blockIdx.x * blockDim.x + threadIdx.x; e < E; e += stride) {
        int d = dst[e];
        int pos = atomicAdd(&cursor[d], 1);
        col[pos] = src[e];
    }
}

// ---------------- GEMM1: [M,256] @ [256,128], scale rows by dinv ----------------
// As stored k-major [32][132] (row stride 528 B, 16B-aligned) so the per-kk
// A-fragment is 2x ds_read_b128 broadcast across 16-lane groups (conflict-free).
// Write side: 4x b32 scatter, ~4-way conflict, but only 4 writes vs 32 kk reads.
__global__ __launch_bounds__(256) void k_gemm1(const float* __restrict__ X,
                                               const float* __restrict__ W,
                                               const float* __restrict__ dinv,
                                               float* __restrict__ H, int M) {
    __shared__ float As[32][132];   // k-major
    __shared__ float Bs[32][128];
    int t = threadIdx.x;
    int tx = t & 15, ty = t >> 4;
    int row0 = blockIdx.x * 128;

    float acc[8][8];
#pragma unroll
    for (int i = 0; i < 8; i++)
#pragma unroll
        for (int j = 0; j < 8; j++) acc[i][j] = 0.f;

    int arow = t >> 3;          // 0..31
    int acol = (t & 7) * 4;     // 0..28 (k within tile)
    int brow = t >> 5;          // 0..7
    int bcol = (t & 31) * 4;    // 0..124

    for (int k0 = 0; k0 < NFEAT; k0 += 32) {
#pragma unroll
        for (int p = 0; p < 4; p++) {
            int r = p * 32 + arow;
            int gr = row0 + r;
            float4 v = make_float4(0.f, 0.f, 0.f, 0.f);
            if (gr < M) v = *(const float4*)&X[(size_t)gr * NFEAT + k0 + acol];
            As[acol + 0][r] = v.x; As[acol + 1][r] = v.y;
            As[acol + 2][r] = v.z; As[acol + 3][r] = v.w;
        }
#pragma unroll
        for (int p = 0; p < 4; p++) {
            int kr = p * 8 + brow;
            *(float4*)&Bs[kr][bcol] = *(const float4*)&W[(size_t)(k0 + kr) * HID + bcol];
        }
        __syncthreads();
#pragma unroll
        for (int kk = 0; kk < 32; kk++) {
            float a[8], b[8];
            *(float4*)&a[0] = *(const float4*)&As[kk][ty * 8];
            *(float4*)&a[4] = *(const float4*)&As[kk][ty * 8 + 4];
            *(float4*)&b[0] = *(const float4*)&Bs[kk][tx * 4];
            *(float4*)&b[4] = *(const float4*)&Bs[kk][64 + tx * 4];
#pragma unroll
            for (int i = 0; i < 8; i++)
#pragma unroll
                for (int j = 0; j < 8; j++) acc[i][j] += a[i] * b[j];
        }
        __syncthreads();
    }
#pragma unroll
    for (int i = 0; i < 8; i++) {
        int gr = row0 + ty * 8 + i;
        if (gr < M) {
            float dv = dinv[gr];
            float4 v0 = make_float4(acc[i][0] * dv, acc[i][1] * dv, acc[i][2] * dv, acc[i][3] * dv);
            float4 v1 = make_float4(acc[i][4] * dv, acc[i][5] * dv, acc[i][6] * dv, acc[i][7] * dv);
            *(float4*)&H[(size_t)gr * HID + tx * 4] = v0;
            *(float4*)&H[(size_t)gr * HID + 64 + tx * 4] = v1;
        }
    }
}

// ---------------- aggregation layer1 (wave per node, 128 feats = 2/lane) ----------------
__global__ __launch_bounds__(256) void k_agg1(const float* __restrict__ H1,
                                              const int* __restrict__ rowptr,
                                              const int* __restrict__ col,
                                              const float* __restrict__ dinv,
                                              const float* __restrict__ b1,
                                              float* __restrict__ out, int N) {
    int node = blockIdx.x * 4 + (threadIdx.x >> 6);
    if (node >= N) return;
    int lane = threadIdx.x & 63;
    int f = lane * 2;

    float2 acc = *(const float2*)&H1[(size_t)node * HID + f];  // self loop (prescaled)
    int e = rowptr[node], e1 = rowptr[node + 1];
    for (; e + 3 < e1; e += 4) {
        int s0 = col[e], s1 = col[e + 1], s2 = col[e + 2], s3 = col[e + 3];
        float2 v0 = *(const float2*)&H1[(size_t)s0 * HID + f];
        float2 v1 = *(const float2*)&H1[(size_t)s1 * HID + f];
        float2 v2 = *(const float2*)&H1[(size_t)s2 * HID + f];
        float2 v3 = *(const float2*)&H1[(size_t)s3 * HID + f];
        acc.x += (v0.x + v1.x) + (v2.x + v3.x);
        acc.y += (v0.y + v1.y) + (v2.y + v3.y);
    }
    for (; e < e1; e++) {
        int s0 = col[e];
        float2 v0 = *(const float2*)&H1[(size_t)s0 * HID + f];
        acc.x += v0.x;
        acc.y += v0.y;
    }
    float dv = dinv[node];
    float2 r;
    r.x = fmaxf(acc.x * dv + b1[f], 0.f);
    r.y = fmaxf(acc.y * dv + b1[f + 1], 0.f);
    *(float2*)&out[(size_t)node * HID + f] = r;
}

// ---------------- GEMM2: [M,128] @ [128,40], W2 fully in LDS ----------------
__global__ __launch_bounds__(256) void k_gemm2(const float* __restrict__ A,
                                               const float* __restrict__ W,
                                               const float* __restrict__ dinv,
                                               float* __restrict__ H, int M) {
    __shared__ float As[64][129];          // pad: conflict-free
    __shared__ float Ws[HID * NCLS];       // 20 KB
    int t = threadIdx.x;
    for (int idx = t; idx < HID * NCLS; idx += 256) Ws[idx] = W[idx];

    int row0 = blockIdx.x * 64;
#pragma unroll
    for (int p = 0; p < 8; p++) {
        int flat = (p * 256 + t) * 4;      // 64*128 floats
        int r = flat >> 7;                 // /128
        int c = flat & 127;
        int gr = row0 + r;
        float4 v = make_float4(0.f, 0.f, 0.f, 0.f);
        if (gr < M) v = *(const float4*)&A[(size_t)gr * HID + c];
        As[r][c + 0] = v.x; As[r][c + 1] = v.y; As[r][c + 2] = v.z; As[r][c + 3] = v.w;
    }
    __syncthreads();

    int r = t >> 2;            // 0..63
    int cg = (t & 3) * 10;     // col group base
    float acc[10];
#pragma unroll
    for (int j = 0; j < 10; j++) acc[j] = 0.f;
    for (int k = 0; k < HID; k++) {
        float a = As[r][k];
        const float* wrow = &Ws[k * NCLS + cg];
#pragma unroll
        for (int j = 0; j < 10; j++) acc[j] += a * wrow[j];
    }
    int gr = row0 + r;
    if (gr < M) {
        float dv = dinv[gr];
#pragma unroll
        for (int j = 0; j < 10; j++) H[(size_t)gr * NCLS + cg + j] = acc[j] * dv;
    }
}

// ---------------- aggregation layer2 (wave per node, 40 feats) ----------------
__global__ __launch_bounds__(256) void k_agg2(const float* __restrict__ H2,
                                              const int* __restrict__ rowptr,
                                              const int* __restrict__ col,
                                              const float* __restrict__ dinv,
                                              const float* __restrict__ b2,
                                              float* __restrict__ out, int N) {
    int node = blockIdx.x * 4 + (threadIdx.x >> 6);
    if (node >= N) return;
    int lane = threadIdx.x & 63;
    bool act = lane < NCLS;

    float acc = act ? H2[(size_t)node * NCLS + lane] : 0.f;  // self loop
    int e = rowptr[node], e1 = rowptr[node + 1];
    for (; e < e1; e++) {
        int s = col[e];
        if (act) acc += H2[(size_t)s * NCLS + lane];
    }
    if (act) out[(size_t)node * NCLS + lane] = acc * dinv[node] + b2[lane];
}

extern "C" void kernel_launch(void* const* d_in, const int* in_sizes, int n_in,
                              void* d_out, int out_size, void* d_ws, size_t ws_size,
                              hipStream_t stream) {
    const float* x  = (const float*)d_in[0];
    const int*   ei = (const int*)d_in[1];   // harness uploads integer inputs as int32
    const float* W1 = (const float*)d_in[2];
    const float* b1 = (const float*)d_in[3];
    const float* W2 = (const float*)d_in[4];
    const float* b2 = (const float*)d_in[5];
    float* out = (float*)d_out;

    const int N = in_sizes[0] / NFEAT;     // 100000
    const int E = in_sizes[1] / 2;         // 1600000
    const int* src = ei;
    const int* dst = ei + E;

    // workspace layout (256B aligned), total ~110.5 MB
    char* ws = (char*)d_ws;
    size_t off = 0;
    auto alloc = [&](size_t bytes) { size_t cur = off; off = (off + bytes + 255) & ~255ULL; return cur; };
    int*   deg       = (int*)(ws + alloc((size_t)N * 4));
    int*   rowptr    = (int*)(ws + alloc(((size_t)N + 1) * 4));
    int*   cursor    = (int*)(ws + alloc((size_t)N * 4));
    float* dinv      = (float*)(ws + alloc((size_t)N * 4));
    int*   blockSums = (int*)(ws + alloc(4096));
    int*   colv      = (int*)(ws + alloc((size_t)E * 4));
    float* h1s       = (float*)(ws + alloc((size_t)N * HID * 4));
    float* hrelu     = (float*)(ws + alloc((size_t)N * HID * 4));
    float* h2s       = h1s;  // reuse: h1s dead after k_agg1

    hipMemsetAsync(deg, 0, (size_t)N * 4, stream);

    k_hist<<<2048, 256, 0, stream>>>(dst, deg, E);

    int nscan = (N + 1023) / 1024;  // 98
    k_scan1<<<nscan, 256, 0, stream>>>(deg, rowptr, blockSums, dinv, N);
    k_scan2<<<1, 128, 0, stream>>>(blockSums, rowptr, nscan, N);
    k_scan3<<<(N + 255) / 256, 256, 0, stream>>>(rowptr, blockSums, cursor, N);

    k_fill<<<4096, 256, 0, stream>>>(src, dst, cursor, colv, E);

    k_gemm1<<<(N + 127) / 128, 256, 0, stream>>>(x, W1, dinv, h1s, N);
    k_agg1<<<(N + 3) / 4, 256, 0, stream>>>(h1s, rowptr, colv, dinv, b1, hrelu, N);
    k_gemm2<<<(N + 63) / 64, 256, 0, stream>>>(hrelu, W2, dinv, h2s, N);
    k_agg2<<<(N + 3) / 4, 256, 0, stream>>>(h2s, rowptr, colv, dinv, b2, out, N);
}

// Round 4
// 655.799 us; speedup vs baseline: 1.1653x; 1.1653x over previous
//
#include <hip/hip_runtime.h>

// GCN 2-layer forward for MI355X.
// edge_index arrives as int32 (harness converts integer inputs).
// Pipeline:
//  1. memset deg=0
//  2. k_hist: deg[dst]++ over edges (int atomics)
//  3. k_scan1/2/3: exclusive scan of deg -> rowptr (CSR), cursor=rowptr, dinv=rsqrt(deg+1)
//  4. k_fill: CSR column fill via atomic cursor
//  5. k_gemm1: h1s = (X @ W1) * dinv[row]      (f32, 128x128x32 LDS tile, k-major A)
//  6. k_agg1:  hrelu = relu(dinv*(sum h1s[src] + h1s[self]) + b1)
//              wave/node, 2 rows/iter x unroll4 = 8 rows in flight, float4 lanes
//  7. k_gemm2: h2s = (hrelu @ W2) * dinv[row]  (W2 fully in LDS)
//  8. k_agg2:  out = dinv*(sum h2s[src] + h2s[self]) + b2
//              wave/node, 6 rows/iter x unroll2 = 12 rows in flight, float4 lanes

#define NFEAT 256
#define HID   128
#define NCLS  40

// ---------------- histogram ----------------
__global__ void k_hist(const int* __restrict__ dst, int* __restrict__ deg, int E) {
    int stride = gridDim.x * blockDim.x;
    for (int e = blockIdx.x * blockDim.x + threadIdx.x; e < E; e += stride)
        atomicAdd(&deg[dst[e]], 1);
}

// ---------------- scan (1024 elems / block) ----------------
__global__ void k_scan1(const int* __restrict__ deg, int* __restrict__ rowptr,
                        int* __restrict__ blockSums, float* __restrict__ dinv, int N) {
    __shared__ int sums[256];
    int t = threadIdx.x;
    int base = blockIdx.x * 1024 + t * 4;
    int c[4];
#pragma unroll
    for (int j = 0; j < 4; j++) {
        int idx = base + j;
        c[j] = (idx < N) ? deg[idx] : 0;
        if (idx < N) dinv[idx] = rsqrtf((float)(c[j] + 1));
    }
    int s = c[0] + c[1] + c[2] + c[3];
    sums[t] = s;
    __syncthreads();
    for (int off = 1; off < 256; off <<= 1) {
        int v = (t >= off) ? sums[t - off] : 0;
        __syncthreads();
        sums[t] += v;
        __syncthreads();
    }
    int run = sums[t] - s;  // exclusive prefix of this thread's 4
#pragma unroll
    for (int j = 0; j < 4; j++) {
        int idx = base + j;
        if (idx < N) rowptr[idx] = run;
        run += c[j];
    }
    if (t == 255) blockSums[blockIdx.x] = sums[255];
}

__global__ void k_scan2(int* __restrict__ blockSums, int* __restrict__ rowptr,
                        int nblocks, int N) {
    __shared__ int sh[128];
    int t = threadIdx.x;  // blockDim = 128, nblocks <= 128
    int v = (t < nblocks) ? blockSums[t] : 0;
    sh[t] = v;
    __syncthreads();
    for (int off = 1; off < 128; off <<= 1) {
        int u = (t >= off) ? sh[t - off] : 0;
        __syncthreads();
        sh[t] += u;
        __syncthreads();
    }
    blockSums[t] = sh[t] - v;          // exclusive
    if (t == 127) rowptr[N] = sh[127]; // total = E
}

__global__ void k_scan3(int* __restrict__ rowptr, const int* __restrict__ blockSums,
                        int* __restrict__ cursor, int N) {
    int stride = gridDim.x * blockDim.x;
    for (int i = blockIdx.x * blockDim.x + threadIdx.x; i < N; i += stride) {
        int v = rowptr[i] + blockSums[i >> 10];
        rowptr[i] = v;
        cursor[i] = v;
    }
}

// ---------------- CSR fill ----------------
__global__ void k_fill(const int* __restrict__ src, const int* __restrict__ dst,
                       int* __restrict__ cursor, int* __restrict__ col, int E) {
    int stride = gridDim.x * blockDim.x;
    for (int e = blockIdx.x * blockDim.x + threadIdx.x; e < E; e += stride) {
        int d = dst[e];
        int pos = atomicAdd(&cursor[d], 1);
        col[pos] = src[e];
    }
}

// ---------------- GEMM1: [M,256] @ [256,128], scale rows by dinv ----------------
// As stored k-major [32][132] so the per-kk A-fragment is 2x ds_read_b128.
__global__ __launch_bounds__(256) void k_gemm1(const float* __restrict__ X,
                                               const float* __restrict__ W,
                                               const float* __restrict__ dinv,
                                               float* __restrict__ H, int M) {
    __shared__ float As[32][132];   // k-major
    __shared__ float Bs[32][128];
    int t = threadIdx.x;
    int tx = t & 15, ty = t >> 4;
    int row0 = blockIdx.x * 128;

    float acc[8][8];
#pragma unroll
    for (int i = 0; i < 8; i++)
#pragma unroll
        for (int j = 0; j < 8; j++) acc[i][j] = 0.f;

    int arow = t >> 3;          // 0..31
    int acol = (t & 7) * 4;     // 0..28 (k within tile)
    int brow = t >> 5;          // 0..7
    int bcol = (t & 31) * 4;    // 0..124

    for (int k0 = 0; k0 < NFEAT; k0 += 32) {
#pragma unroll
        for (int p = 0; p < 4; p++) {
            int r = p * 32 + arow;
            int gr = row0 + r;
            float4 v = make_float4(0.f, 0.f, 0.f, 0.f);
            if (gr < M) v = *(const float4*)&X[(size_t)gr * NFEAT + k0 + acol];
            As[acol + 0][r] = v.x; As[acol + 1][r] = v.y;
            As[acol + 2][r] = v.z; As[acol + 3][r] = v.w;
        }
#pragma unroll
        for (int p = 0; p < 4; p++) {
            int kr = p * 8 + brow;
            *(float4*)&Bs[kr][bcol] = *(const float4*)&W[(size_t)(k0 + kr) * HID + bcol];
        }
        __syncthreads();
#pragma unroll
        for (int kk = 0; kk < 32; kk++) {
            float a[8], b[8];
            *(float4*)&a[0] = *(const float4*)&As[kk][ty * 8];
            *(float4*)&a[4] = *(const float4*)&As[kk][ty * 8 + 4];
            *(float4*)&b[0] = *(const float4*)&Bs[kk][tx * 4];
            *(float4*)&b[4] = *(const float4*)&Bs[kk][64 + tx * 4];
#pragma unroll
            for (int i = 0; i < 8; i++)
#pragma unroll
                for (int j = 0; j < 8; j++) acc[i][j] += a[i] * b[j];
        }
        __syncthreads();
    }
#pragma unroll
    for (int i = 0; i < 8; i++) {
        int gr = row0 + ty * 8 + i;
        if (gr < M) {
            float dv = dinv[gr];
            float4 v0 = make_float4(acc[i][0] * dv, acc[i][1] * dv, acc[i][2] * dv, acc[i][3] * dv);
            float4 v1 = make_float4(acc[i][4] * dv, acc[i][5] * dv, acc[i][6] * dv, acc[i][7] * dv);
            *(float4*)&H[(size_t)gr * HID + tx * 4] = v0;
            *(float4*)&H[(size_t)gr * HID + 64 + tx * 4] = v1;
        }
    }
}

// ---------------- aggregation layer1 ----------------
// wave per node. g = lane>>5 selects edge slot (2 rows/iter), c = lane&31 is a
// float4 chunk (32 lanes x 16B = full 512B row). unroll 4 -> 8 rows in flight.
__global__ __launch_bounds__(256) void k_agg1(const float* __restrict__ H1,
                                              const int* __restrict__ rowptr,
                                              const int* __restrict__ col,
                                              const float* __restrict__ dinv,
                                              const float* __restrict__ b1,
                                              float* __restrict__ out, int N) {
    int node = blockIdx.x * 4 + (threadIdx.x >> 6);
    if (node >= N) return;
    int lane = threadIdx.x & 63;
    int g = lane >> 5;          // 0..1
    int c = lane & 31;          // float4 index within row

    float4 acc = make_float4(0.f, 0.f, 0.f, 0.f);
    if (g == 0)  // self loop (prescaled) counted once
        acc = *(const float4*)&H1[(size_t)node * HID + c * 4];

    int e = rowptr[node], e1 = rowptr[node + 1];
    for (; e + 7 < e1; e += 8) {
        int s0 = col[e + g];
        int s1 = col[e + 2 + g];
        int s2 = col[e + 4 + g];
        int s3 = col[e + 6 + g];
        float4 v0 = *(const float4*)&H1[(size_t)s0 * HID + c * 4];
        float4 v1 = *(const float4*)&H1[(size_t)s1 * HID + c * 4];
        float4 v2 = *(const float4*)&H1[(size_t)s2 * HID + c * 4];
        float4 v3 = *(const float4*)&H1[(size_t)s3 * HID + c * 4];
        acc.x += (v0.x + v1.x) + (v2.x + v3.x);
        acc.y += (v0.y + v1.y) + (v2.y + v3.y);
        acc.z += (v0.z + v1.z) + (v2.z + v3.z);
        acc.w += (v0.w + v1.w) + (v2.w + v3.w);
    }
    for (; e + 1 < e1; e += 2) {
        int s = col[e + g];
        float4 v = *(const float4*)&H1[(size_t)s * HID + c * 4];
        acc.x += v.x; acc.y += v.y; acc.z += v.z; acc.w += v.w;
    }
    if (e < e1 && g == 0) {     // odd remaining edge
        int s = col[e];
        float4 v = *(const float4*)&H1[(size_t)s * HID + c * 4];
        acc.x += v.x; acc.y += v.y; acc.z += v.z; acc.w += v.w;
    }
    // combine the two edge slots
    acc.x += __shfl_xor(acc.x, 32);
    acc.y += __shfl_xor(acc.y, 32);
    acc.z += __shfl_xor(acc.z, 32);
    acc.w += __shfl_xor(acc.w, 32);

    if (g == 0) {
        float dv = dinv[node];
        float4 bb = *(const float4*)&b1[c * 4];
        float4 r;
        r.x = fmaxf(acc.x * dv + bb.x, 0.f);
        r.y = fmaxf(acc.y * dv + bb.y, 0.f);
        r.z = fmaxf(acc.z * dv + bb.z, 0.f);
        r.w = fmaxf(acc.w * dv + bb.w, 0.f);
        *(float4*)&out[(size_t)node * HID + c * 4] = r;
    }
}

// ---------------- GEMM2: [M,128] @ [128,40], W2 fully in LDS ----------------
__global__ __launch_bounds__(256) void k_gemm2(const float* __restrict__ A,
                                               const float* __restrict__ W,
                                               const float* __restrict__ dinv,
                                               float* __restrict__ H, int M) {
    __shared__ float As[64][129];          // pad: conflict-free
    __shared__ float Ws[HID * NCLS];       // 20 KB
    int t = threadIdx.x;
    for (int idx = t; idx < HID * NCLS; idx += 256) Ws[idx] = W[idx];

    int row0 = blockIdx.x * 64;
#pragma unroll
    for (int p = 0; p < 8; p++) {
        int flat = (p * 256 + t) * 4;      // 64*128 floats
        int r = flat >> 7;                 // /128
        int c = flat & 127;
        int gr = row0 + r;
        float4 v = make_float4(0.f, 0.f, 0.f, 0.f);
        if (gr < M) v = *(const float4*)&A[(size_t)gr * HID + c];
        As[r][c + 0] = v.x; As[r][c + 1] = v.y; As[r][c + 2] = v.z; As[r][c + 3] = v.w;
    }
    __syncthreads();

    int r = t >> 2;            // 0..63
    int cg = (t & 3) * 10;     // col group base
    float acc[10];
#pragma unroll
    for (int j = 0; j < 10; j++) acc[j] = 0.f;
    for (int k = 0; k < HID; k++) {
        float a = As[r][k];
        const float* wrow = &Ws[k * NCLS + cg];
#pragma unroll
        for (int j = 0; j < 10; j++) acc[j] += a * wrow[j];
    }
    int gr = row0 + r;
    if (gr < M) {
        float dv = dinv[gr];
#pragma unroll
        for (int j = 0; j < 10; j++) H[(size_t)gr * NCLS + cg + j] = acc[j] * dv;
    }
}

// ---------------- aggregation layer2 ----------------
// wave per node. g = lane/10 selects edge slot (6 rows/iter), c = lane%10 is a
// float4 chunk (10 lanes x 16B = full 160B row). unroll 2 -> 12 rows in flight.
__global__ __launch_bounds__(256) void k_agg2(const float* __restrict__ H2,
                                              const int* __restrict__ rowptr,
                                              const int* __restrict__ col,
                                              const float* __restrict__ dinv,
                                              const float* __restrict__ b2,
                                              float* __restrict__ out, int N) {
    int node = blockIdx.x * 4 + (threadIdx.x >> 6);
    if (node >= N) return;
    int lane = threadIdx.x & 63;
    int g = lane / 10;          // 0..6 (g==6 -> lanes 60..63 idle)
    int c = lane % 10;          // float4 index within 40-float row
    bool active = g < 6;

    float4 acc = make_float4(0.f, 0.f, 0.f, 0.f);
    if (g == 0)  // self loop (prescaled)
        acc = *(const float4*)&H2[(size_t)node * NCLS + c * 4];

    int e = rowptr[node], e1 = rowptr[node + 1];
    for (; e + 11 < e1; e += 12) {
        if (active) {
            int s0 = col[e + g];
            int s1 = col[e + 6 + g];
            float4 v0 = *(const float4*)&H2[(size_t)s0 * NCLS + c * 4];
            float4 v1 = *(const float4*)&H2[(size_t)s1 * NCLS + c * 4];
            acc.x += v0.x + v1.x;
            acc.y += v0.y + v1.y;
            acc.z += v0.z + v1.z;
            acc.w += v0.w + v1.w;
        }
    }
    for (; e < e1; e += 6) {
        int idx = e + g;
        if (active && idx < e1) {
            int s = col[idx];
            float4 v = *(const float4*)&H2[(size_t)s * NCLS + c * 4];
            acc.x += v.x; acc.y += v.y; acc.z += v.z; acc.w += v.w;
        }
    }
    // reduce 6 groups -> group 0. Step 1: g(0,1,2) += g(3,4,5).
    float4 t1, t2;
    t1.x = __shfl(acc.x, lane + 30); t1.y = __shfl(acc.y, lane + 30);
    t1.z = __shfl(acc.z, lane + 30); t1.w = __shfl(acc.w, lane + 30);
    acc.x += t1.x; acc.y += t1.y; acc.z += t1.z; acc.w += t1.w;
    // Step 2: g0 += g1 + g2 (capture both before mutating).
    t1.x = __shfl(acc.x, lane + 10); t1.y = __shfl(acc.y, lane + 10);
    t1.z = __shfl(acc.z, lane + 10); t1.w = __shfl(acc.w, lane + 10);
    t2.x = __shfl(acc.x, lane + 20); t2.y = __shfl(acc.y, lane + 20);
    t2.z = __shfl(acc.z, lane + 20); t2.w = __shfl(acc.w, lane + 20);
    acc.x += t1.x + t2.x; acc.y += t1.y + t2.y;
    acc.z += t1.z + t2.z; acc.w += t1.w + t2.w;

    if (g == 0) {
        float dv = dinv[node];
        float4 bb = *(const float4*)&b2[c * 4];
        float4 r;
        r.x = acc.x * dv + bb.x;
        r.y = acc.y * dv + bb.y;
        r.z = acc.z * dv + bb.z;
        r.w = acc.w * dv + bb.w;
        *(float4*)&out[(size_t)node * NCLS + c * 4] = r;
    }
}

extern "C" void kernel_launch(void* const* d_in, const int* in_sizes, int n_in,
                              void* d_out, int out_size, void* d_ws, size_t ws_size,
                              hipStream_t stream) {
    const float* x  = (const float*)d_in[0];
    const int*   ei = (const int*)d_in[1];   // int32 edge_index
    const float* W1 = (const float*)d_in[2];
    const float* b1 = (const float*)d_in[3];
    const float* W2 = (const float*)d_in[4];
    const float* b2 = (const float*)d_in[5];
    float* out = (float*)d_out;

    const int N = in_sizes[0] / NFEAT;     // 100000
    const int E = in_sizes[1] / 2;         // 1600000
    const int* src = ei;
    const int* dst = ei + E;

    // workspace layout (256B aligned), total ~110.5 MB
    char* ws = (char*)d_ws;
    size_t off = 0;
    auto alloc = [&](size_t bytes) { size_t cur = off; off = (off + bytes + 255) & ~255ULL; return cur; };
    int*   deg       = (int*)(ws + alloc((size_t)N * 4));
    int*   rowptr    = (int*)(ws + alloc(((size_t)N + 1) * 4));
    int*   cursor    = (int*)(ws + alloc((size_t)N * 4));
    float* dinv      = (float*)(ws + alloc((size_t)N * 4));
    int*   blockSums = (int*)(ws + alloc(4096));
    int*   colv      = (int*)(ws + alloc((size_t)E * 4));
    float* h1s       = (float*)(ws + alloc((size_t)N * HID * 4));
    float* hrelu     = (float*)(ws + alloc((size_t)N * HID * 4));
    float* h2s       = h1s;  // reuse: h1s dead after k_agg1

    hipMemsetAsync(deg, 0, (size_t)N * 4, stream);

    k_hist<<<2048, 256, 0, stream>>>(dst, deg, E);

    int nscan = (N + 1023) / 1024;  // 98
    k_scan1<<<nscan, 256, 0, stream>>>(deg, rowptr, blockSums, dinv, N);
    k_scan2<<<1, 128, 0, stream>>>(blockSums, rowptr, nscan, N);
    k_scan3<<<(N + 255) / 256, 256, 0, stream>>>(rowptr, blockSums, cursor, N);

    k_fill<<<4096, 256, 0, stream>>>(src, dst, cursor, colv, E);

    k_gemm1<<<(N + 127) / 128, 256, 0, stream>>>(x, W1, dinv, h1s, N);
    k_agg1<<<(N + 3) / 4, 256, 0, stream>>>(h1s, rowptr, colv, dinv, b1, hrelu, N);
    k_gemm2<<<(N + 63) / 64, 256, 0, stream>>>(hrelu, W2, dinv, h2s, N);
    k_agg2<<<(N + 3) / 4, 256, 0, stream>>>(h2s, rowptr, colv, dinv, b2, out, N);
}

// Round 5
// 641.370 us; speedup vs baseline: 1.1915x; 1.0225x over previous
//
#include <hip/hip_runtime.h>

// GCN 2-layer forward for MI355X.
// edge_index arrives as int32 (harness converts integer inputs).
// CSR build is bucketed (32 nodes/bucket) to avoid random 4B scatter:
//  1. memset bcount=0
//  2. kA_bhist: bucket histogram via LDS (bucket = dst>>5)
//  3. kB_bscan: scan bucket counts -> bstart, bcursor; rowptr[N]=E
//  4. kC_scatter: stage[pos] = src | (dst&31)<<27, appended per-bucket (4B entries)
//  5. kD_fill: per-bucket LDS deg-hist + scan -> rowptr, dinv, col (2KB window writes)
// then:
//  6. k_gemm1: h1s = (X @ W1) * dinv[row]      (f32, 128x128x32 LDS tile, k-major A)
//  7. k_agg1:  hrelu = relu(dinv*(sum h1s[src] + h1s[self]) + b1)
//  8. k_gemm2: h2s = (hrelu @ W2) * dinv[row]
//  9. k_agg2:  out = dinv*(sum h2s[src] + h2s[self]) + b2

#define NFEAT 256
#define HID   128
#define NCLS  40
#define NBMAX 3136   // LDS histogram capacity; NB = ceil(N/32) = 3125 for N=100000

// ---------------- bucket histogram ----------------
__global__ __launch_bounds__(256) void kA_bhist(const int* __restrict__ dst,
                                                int* __restrict__ bcount, int E, int NB) {
    __shared__ int hist[NBMAX];
    for (int i = threadIdx.x; i < NB; i += 256) hist[i] = 0;
    __syncthreads();
    int stride = gridDim.x * blockDim.x;
    for (int e = blockIdx.x * blockDim.x + threadIdx.x; e < E; e += stride)
        atomicAdd(&hist[dst[e] >> 5], 1);
    __syncthreads();
    for (int i = threadIdx.x; i < NB; i += 256) {
        int h = hist[i];
        if (h) atomicAdd(&bcount[i], h);
    }
}

// ---------------- bucket scan (single block) ----------------
__global__ __launch_bounds__(256) void kB_bscan(const int* __restrict__ bcount,
                                                int* __restrict__ bstart,
                                                int* __restrict__ bcursor,
                                                int* __restrict__ rowptr,
                                                int NB, int Nn, int E) {
    __shared__ int sums[256];
    int t = threadIdx.x;
    int per = (NB + 255) / 256;
    int base = t * per;
    int s = 0;
    for (int j = 0; j < per; j++) {
        int i = base + j;
        if (i < NB) s += bcount[i];
    }
    sums[t] = s;
    __syncthreads();
    for (int off = 1; off < 256; off <<= 1) {
        int v = (t >= off) ? sums[t - off] : 0;
        __syncthreads();
        sums[t] += v;
        __syncthreads();
    }
    int run = sums[t] - s;   // exclusive prefix
    for (int j = 0; j < per; j++) {
        int i = base + j;
        if (i < NB) { bstart[i] = run; bcursor[i] = run; run += bcount[i]; }
    }
    if (t == 255) { bstart[NB] = run; rowptr[Nn] = E; }
}

// ---------------- edge scatter into buckets ----------------
__global__ __launch_bounds__(256) void kC_scatter(const int* __restrict__ src,
                                                  const int* __restrict__ dst,
                                                  int* __restrict__ bcursor,
                                                  unsigned int* __restrict__ stage, int E) {
    int stride = gridDim.x * blockDim.x;
    for (int e = blockIdx.x * blockDim.x + threadIdx.x; e < E; e += stride) {
        int d = dst[e];
        int pos = atomicAdd(&bcursor[d >> 5], 1);
        stage[pos] = (unsigned int)src[e] | ((unsigned int)(d & 31) << 27);
    }
}

// ---------------- per-bucket CSR fill ----------------
__global__ __launch_bounds__(256) void kD_fill(const unsigned int* __restrict__ stage,
                                               const int* __restrict__ bstart,
                                               int* __restrict__ rowptr,
                                               float* __restrict__ dinv,
                                               int* __restrict__ col, int Nn) {
    __shared__ int deg32[32];
    __shared__ int pref[32];
    __shared__ int cur[32];
    int b = blockIdx.x;
    int t = threadIdx.x;
    int bs = bstart[b], be = bstart[b + 1];
    if (t < 32) deg32[t] = 0;
    __syncthreads();
    for (int i = bs + t; i < be; i += 256) {
        unsigned int u = stage[i];
        atomicAdd(&deg32[u >> 27], 1);
    }
    __syncthreads();
    if (t == 0) {
        int r = 0;
        for (int j = 0; j < 32; j++) { pref[j] = r; r += deg32[j]; }
    }
    __syncthreads();
    int n0 = b * 32;
    if (t < 32) {
        int n = n0 + t;
        if (n < Nn) {
            rowptr[n] = bs + pref[t];
            dinv[n] = rsqrtf((float)(deg32[t] + 1));
        }
        cur[t] = pref[t];
    }
    __syncthreads();
    for (int i = bs + t; i < be; i += 256) {
        unsigned int u = stage[i];
        int d = u >> 27;
        int pos = bs + atomicAdd(&cur[d], 1);
        col[pos] = (int)(u & 0x07FFFFFFu);
    }
}

// ---------------- GEMM1: [M,256] @ [256,128], scale rows by dinv ----------------
// As stored k-major [32][132] so the per-kk A-fragment is 2x ds_read_b128.
__global__ __launch_bounds__(256) void k_gemm1(const float* __restrict__ X,
                                               const float* __restrict__ W,
                                               const float* __restrict__ dinv,
                                               float* __restrict__ H, int M) {
    __shared__ float As[32][132];   // k-major
    __shared__ float Bs[32][128];
    int t = threadIdx.x;
    int tx = t & 15, ty = t >> 4;
    int row0 = blockIdx.x * 128;

    float acc[8][8];
#pragma unroll
    for (int i = 0; i < 8; i++)
#pragma unroll
        for (int j = 0; j < 8; j++) acc[i][j] = 0.f;

    int arow = t >> 3;          // 0..31
    int acol = (t & 7) * 4;     // 0..28 (k within tile)
    int brow = t >> 5;          // 0..7
    int bcol = (t & 31) * 4;    // 0..124

    for (int k0 = 0; k0 < NFEAT; k0 += 32) {
#pragma unroll
        for (int p = 0; p < 4; p++) {
            int r = p * 32 + arow;
            int gr = row0 + r;
            float4 v = make_float4(0.f, 0.f, 0.f, 0.f);
            if (gr < M) v = *(const float4*)&X[(size_t)gr * NFEAT + k0 + acol];
            As[acol + 0][r] = v.x; As[acol + 1][r] = v.y;
            As[acol + 2][r] = v.z; As[acol + 3][r] = v.w;
        }
#pragma unroll
        for (int p = 0; p < 4; p++) {
            int kr = p * 8 + brow;
            *(float4*)&Bs[kr][bcol] = *(const float4*)&W[(size_t)(k0 + kr) * HID + bcol];
        }
        __syncthreads();
#pragma unroll
        for (int kk = 0; kk < 32; kk++) {
            float a[8], b[8];
            *(float4*)&a[0] = *(const float4*)&As[kk][ty * 8];
            *(float4*)&a[4] = *(const float4*)&As[kk][ty * 8 + 4];
            *(float4*)&b[0] = *(const float4*)&Bs[kk][tx * 4];
            *(float4*)&b[4] = *(const float4*)&Bs[kk][64 + tx * 4];
#pragma unroll
            for (int i = 0; i < 8; i++)
#pragma unroll
                for (int j = 0; j < 8; j++) acc[i][j] += a[i] * b[j];
        }
        __syncthreads();
    }
#pragma unroll
    for (int i = 0; i < 8; i++) {
        int gr = row0 + ty * 8 + i;
        if (gr < M) {
            float dv = dinv[gr];
            float4 v0 = make_float4(acc[i][0] * dv, acc[i][1] * dv, acc[i][2] * dv, acc[i][3] * dv);
            float4 v1 = make_float4(acc[i][4] * dv, acc[i][5] * dv, acc[i][6] * dv, acc[i][7] * dv);
            *(float4*)&H[(size_t)gr * HID + tx * 4] = v0;
            *(float4*)&H[(size_t)gr * HID + 64 + tx * 4] = v1;
        }
    }
}

// ---------------- aggregation layer1 ----------------
// wave per node. g = lane>>5 selects edge slot (2 rows/iter), c = lane&31 is a
// float4 chunk (32 lanes x 16B = full 512B row). unroll 4 -> 8 rows in flight.
__global__ __launch_bounds__(256) void k_agg1(const float* __restrict__ H1,
                                              const int* __restrict__ rowptr,
                                              const int* __restrict__ col,
                                              const float* __restrict__ dinv,
                                              const float* __restrict__ b1,
                                              float* __restrict__ out, int N) {
    int node = blockIdx.x * 4 + (threadIdx.x >> 6);
    if (node >= N) return;
    int lane = threadIdx.x & 63;
    int g = lane >> 5;          // 0..1
    int c = lane & 31;          // float4 index within row

    float4 acc = make_float4(0.f, 0.f, 0.f, 0.f);
    if (g == 0)  // self loop (prescaled) counted once
        acc = *(const float4*)&H1[(size_t)node * HID + c * 4];

    int e = rowptr[node], e1 = rowptr[node + 1];
    for (; e + 7 < e1; e += 8) {
        int s0 = col[e + g];
        int s1 = col[e + 2 + g];
        int s2 = col[e + 4 + g];
        int s3 = col[e + 6 + g];
        float4 v0 = *(const float4*)&H1[(size_t)s0 * HID + c * 4];
        float4 v1 = *(const float4*)&H1[(size_t)s1 * HID + c * 4];
        float4 v2 = *(const float4*)&H1[(size_t)s2 * HID + c * 4];
        float4 v3 = *(const float4*)&H1[(size_t)s3 * HID + c * 4];
        acc.x += (v0.x + v1.x) + (v2.x + v3.x);
        acc.y += (v0.y + v1.y) + (v2.y + v3.y);
        acc.z += (v0.z + v1.z) + (v2.z + v3.z);
        acc.w += (v0.w + v1.w) + (v2.w + v3.w);
    }
    for (; e + 1 < e1; e += 2) {
        int s = col[e + g];
        float4 v = *(const float4*)&H1[(size_t)s * HID + c * 4];
        acc.x += v.x; acc.y += v.y; acc.z += v.z; acc.w += v.w;
    }
    if (e < e1 && g == 0) {     // odd remaining edge
        int s = col[e];
        float4 v = *(const float4*)&H1[(size_t)s * HID + c * 4];
        acc.x += v.x; acc.y += v.y; acc.z += v.z; acc.w += v.w;
    }
    // combine the two edge slots
    acc.x += __shfl_xor(acc.x, 32);
    acc.y += __shfl_xor(acc.y, 32);
    acc.z += __shfl_xor(acc.z, 32);
    acc.w += __shfl_xor(acc.w, 32);

    if (g == 0) {
        float dv = dinv[node];
        float4 bb = *(const float4*)&b1[c * 4];
        float4 r;
        r.x = fmaxf(acc.x * dv + bb.x, 0.f);
        r.y = fmaxf(acc.y * dv + bb.y, 0.f);
        r.z = fmaxf(acc.z * dv + bb.z, 0.f);
        r.w = fmaxf(acc.w * dv + bb.w, 0.f);
        *(float4*)&out[(size_t)node * HID + c * 4] = r;
    }
}

// ---------------- GEMM2: [M,128] @ [128,40], W2 fully in LDS ----------------
__global__ __launch_bounds__(256) void k_gemm2(const float* __restrict__ A,
                                               const float* __restrict__ W,
                                               const float* __restrict__ dinv,
                                               float* __restrict__ H, int M) {
    __shared__ float As[64][129];          // pad: conflict-free
    __shared__ float Ws[HID * NCLS];       // 20 KB
    int t = threadIdx.x;
    for (int idx = t; idx < HID * NCLS; idx += 256) Ws[idx] = W[idx];

    int row0 = blockIdx.x * 64;
#pragma unroll
    for (int p = 0; p < 8; p++) {
        int flat = (p * 256 + t) * 4;      // 64*128 floats
        int r = flat >> 7;                 // /128
        int c = flat & 127;
        int gr = row0 + r;
        float4 v = make_float4(0.f, 0.f, 0.f, 0.f);
        if (gr < M) v = *(const float4*)&A[(size_t)gr * HID + c];
        As[r][c + 0] = v.x; As[r][c + 1] = v.y; As[r][c + 2] = v.z; As[r][c + 3] = v.w;
    }
    __syncthreads();

    int r = t >> 2;            // 0..63
    int cg = (t & 3) * 10;     // col group base
    float acc[10];
#pragma unroll
    for (int j = 0; j < 10; j++) acc[j] = 0.f;
    for (int k = 0; k < HID; k++) {
        float a = As[r][k];
        const float* wrow = &Ws[k * NCLS + cg];
#pragma unroll
        for (int j = 0; j < 10; j++) acc[j] += a * wrow[j];
    }
    int gr = row0 + r;
    if (gr < M) {
        float dv = dinv[gr];
#pragma unroll
        for (int j = 0; j < 10; j++) H[(size_t)gr * NCLS + cg + j] = acc[j] * dv;
    }
}

// ---------------- aggregation layer2 ----------------
// wave per node. g = lane/10 selects edge slot (6 rows/iter), c = lane%10 is a
// float4 chunk (10 lanes x 16B = full 160B row). unroll 2 -> 12 rows in flight.
__global__ __launch_bounds__(256) void k_agg2(const float* __restrict__ H2,
                                              const int* __restrict__ rowptr,
                                              const int* __restrict__ col,
                                              const float* __restrict__ dinv,
                                              const float* __restrict__ b2,
                                              float* __restrict__ out, int N) {
    int node = blockIdx.x * 4 + (threadIdx.x >> 6);
    if (node >= N) return;
    int lane = threadIdx.x & 63;
    int g = lane / 10;          // 0..6 (g==6 -> lanes 60..63 idle)
    int c = lane % 10;          // float4 index within 40-float row
    bool active = g < 6;

    float4 acc = make_float4(0.f, 0.f, 0.f, 0.f);
    if (g == 0)  // self loop (prescaled)
        acc = *(const float4*)&H2[(size_t)node * NCLS + c * 4];

    int e = rowptr[node], e1 = rowptr[node + 1];
    for (; e + 11 < e1; e += 12) {
        if (active) {
            int s0 = col[e + g];
            int s1 = col[e + 6 + g];
            float4 v0 = *(const float4*)&H2[(size_t)s0 * NCLS + c * 4];
            float4 v1 = *(const float4*)&H2[(size_t)s1 * NCLS + c * 4];
            acc.x += v0.x + v1.x;
            acc.y += v0.y + v1.y;
            acc.z += v0.z + v1.z;
            acc.w += v0.w + v1.w;
        }
    }
    for (; e < e1; e += 6) {
        int idx = e + g;
        if (active && idx < e1) {
            int s = col[idx];
            float4 v = *(const float4*)&H2[(size_t)s * NCLS + c * 4];
            acc.x += v.x; acc.y += v.y; acc.z += v.z; acc.w += v.w;
        }
    }
    // reduce 6 groups -> group 0. Step 1: g(0,1,2) += g(3,4,5).
    float4 t1, t2;
    t1.x = __shfl(acc.x, lane + 30); t1.y = __shfl(acc.y, lane + 30);
    t1.z = __shfl(acc.z, lane + 30); t1.w = __shfl(acc.w, lane + 30);
    acc.x += t1.x; acc.y += t1.y; acc.z += t1.z; acc.w += t1.w;
    // Step 2: g0 += g1 + g2 (capture both before mutating).
    t1.x = __shfl(acc.x, lane + 10); t1.y = __shfl(acc.y, lane + 10);
    t1.z = __shfl(acc.z, lane + 10); t1.w = __shfl(acc.w, lane + 10);
    t2.x = __shfl(acc.x, lane + 20); t2.y = __shfl(acc.y, lane + 20);
    t2.z = __shfl(acc.z, lane + 20); t2.w = __shfl(acc.w, lane + 20);
    acc.x += t1.x + t2.x; acc.y += t1.y + t2.y;
    acc.z += t1.z + t2.z; acc.w += t1.w + t2.w;

    if (g == 0) {
        float dv = dinv[node];
        float4 bb = *(const float4*)&b2[c * 4];
        float4 r;
        r.x = acc.x * dv + bb.x;
        r.y = acc.y * dv + bb.y;
        r.z = acc.z * dv + bb.z;
        r.w = acc.w * dv + bb.w;
        *(float4*)&out[(size_t)node * NCLS + c * 4] = r;
    }
}

extern "C" void kernel_launch(void* const* d_in, const int* in_sizes, int n_in,
                              void* d_out, int out_size, void* d_ws, size_t ws_size,
                              hipStream_t stream) {
    const float* x  = (const float*)d_in[0];
    const int*   ei = (const int*)d_in[1];   // int32 edge_index
    const float* W1 = (const float*)d_in[2];
    const float* b1 = (const float*)d_in[3];
    const float* W2 = (const float*)d_in[4];
    const float* b2 = (const float*)d_in[5];
    float* out = (float*)d_out;

    const int N = in_sizes[0] / NFEAT;     // 100000
    const int E = in_sizes[1] / 2;         // 1600000
    const int NB = (N + 31) / 32;          // 3125
    const int* src = ei;
    const int* dst = ei + E;

    // workspace layout (256B aligned)
    char* ws = (char*)d_ws;
    size_t off = 0;
    auto alloc = [&](size_t bytes) { size_t cur = off; off = (off + bytes + 255) & ~255ULL; return cur; };
    int*   rowptr  = (int*)(ws + alloc(((size_t)N + 1) * 4));
    float* dinv    = (float*)(ws + alloc((size_t)N * 4));
    int*   bcount  = (int*)(ws + alloc(((size_t)NB + 1) * 4));
    int*   bstart  = (int*)(ws + alloc(((size_t)NB + 1) * 4));
    int*   bcursor = (int*)(ws + alloc(((size_t)NB + 1) * 4));
    int*   colv    = (int*)(ws + alloc((size_t)E * 4));
    float* h1s     = (float*)(ws + alloc((size_t)N * HID * 4));
    float* hrelu   = (float*)(ws + alloc((size_t)N * HID * 4));
    float* h2s     = h1s;                          // reuse: h1s dead after k_agg1
    unsigned int* stage = (unsigned int*)hrelu;    // reuse: stage dead before k_agg1 writes hrelu

    hipMemsetAsync(bcount, 0, ((size_t)NB + 1) * 4, stream);

    kA_bhist<<<128, 256, 0, stream>>>(dst, bcount, E, NB);
    kB_bscan<<<1, 256, 0, stream>>>(bcount, bstart, bcursor, rowptr, NB, N, E);
    kC_scatter<<<2048, 256, 0, stream>>>(src, dst, bcursor, stage, E);
    kD_fill<<<NB, 256, 0, stream>>>(stage, bstart, rowptr, dinv, colv, N);

    k_gemm1<<<(N + 127) / 128, 256, 0, stream>>>(x, W1, dinv, h1s, N);
    k_agg1<<<(N + 3) / 4, 256, 0, stream>>>(h1s, rowptr, colv, dinv, b1, hrelu, N);
    k_gemm2<<<(N + 63) / 64, 256, 0, stream>>>(hrelu, W2, dinv, h2s, N);
    k_agg2<<<(N + 3) / 4, 256, 0, stream>>>(h2s, rowptr, colv, dinv, b2, out, N);
}

// Round 6
// 544.436 us; speedup vs baseline: 1.4037x; 1.1780x over previous
//
#include <hip/hip_runtime.h>

// GCN 2-layer forward for MI355X.
// edge_index arrives as int32 (harness converts integer inputs).
//
// CSR build v3 — chunk-local counting sort (fixes cross-XCD write ping-pong):
//  1. memset bcount=0
//  2. kA_bhist: coarse-bucket histogram (bucket = dst>>9, NB=196) via LDS
//  3. kB_bscan: scan bucket counts -> bstart, bcursor(allocator); rowptr[N]=E
//  4. kP1: per-4096-edge-chunk LDS counting sort; ONE global atomicAdd per
//     (block,bucket) reserves a contiguous run; block writes its own runs of
//     packed 4B entries (src | (dst&511)<<17). Single-writer, line-sized runs.
//  5. kP2: one block per bucket (512 nodes): LDS deg-hist -> LDS scan ->
//     rowptr/dinv -> col fill via LDS cursors into contiguous L2-resident window.
// then:
//  6. k_gemm1: h1s = (X @ W1) * dinv[row]   (f32 128x128x32 tile, k-major A)
//  7. k_agg1:  hrelu = relu(dinv*(sum h1s[src] + h1s[self]) + b1)
//  8. k_gemm2: h2s = (hrelu @ W2) * dinv[row]
//  9. k_agg2:  out = dinv*(sum h2s[src] + h2s[self]) + b2

#define NFEAT 256
#define HID   128
#define NCLS  40
#define BSH   9              // 512 nodes per coarse bucket
#define SRCBITS 17           // N=100000 < 2^17; pack: src | (dst&511)<<17
#define SRCMASK 0x1FFFF
#define CHUNK 4096           // edges per kP1 block (256 thr x 16)

// ---------------- coarse bucket histogram ----------------
__global__ __launch_bounds__(256) void kA_bhist(const int* __restrict__ dst,
                                                int* __restrict__ bcount, int E, int NB) {
    __shared__ int hist[256];
    if (threadIdx.x < NB) hist[threadIdx.x] = 0;
    __syncthreads();
    int stride = gridDim.x * blockDim.x;
    for (int e = blockIdx.x * blockDim.x + threadIdx.x; e < E; e += stride)
        atomicAdd(&hist[dst[e] >> BSH], 1);
    __syncthreads();
    if (threadIdx.x < NB) {
        int h = hist[threadIdx.x];
        if (h) atomicAdd(&bcount[threadIdx.x], h);
    }
}

// ---------------- bucket scan (single block) ----------------
__global__ __launch_bounds__(256) void kB_bscan(const int* __restrict__ bcount,
                                                int* __restrict__ bstart,
                                                int* __restrict__ bcursor,
                                                int* __restrict__ rowptr,
                                                int NB, int Nn, int E) {
    __shared__ int sums[256];
    int t = threadIdx.x;
    int s = (t < NB) ? bcount[t] : 0;
    sums[t] = s;
    __syncthreads();
    for (int off = 1; off < 256; off <<= 1) {
        int v = (t >= off) ? sums[t - off] : 0;
        __syncthreads();
        sums[t] += v;
        __syncthreads();
    }
    int run = sums[t] - s;   // exclusive prefix
    if (t < NB) { bstart[t] = run; bcursor[t] = run; }
    if (t == 255) { bstart[NB] = sums[255]; rowptr[Nn] = E; }
}

// ---------------- chunk-local counting sort into buckets ----------------
__global__ __launch_bounds__(256) void kP1(const int* __restrict__ src,
                                           const int* __restrict__ dst,
                                           int* __restrict__ bcursor,
                                           unsigned int* __restrict__ stage,
                                           int E, int NB) {
    __shared__ int cnt[256];
    __shared__ int base[256];
    int t = threadIdx.x;
    int e0 = blockIdx.x * CHUNK;
    if (t < NB) cnt[t] = 0;
    __syncthreads();
    // count
#pragma unroll
    for (int j = 0; j < CHUNK / 256; j++) {
        int e = e0 + j * 256 + t;
        if (e < E) atomicAdd(&cnt[dst[e] >> BSH], 1);
    }
    __syncthreads();
    // reserve one contiguous run per bucket for this block
    if (t < NB) {
        int c = cnt[t];
        base[t] = c ? atomicAdd(&bcursor[t], c) : 0;
        cnt[t] = 0;   // reuse as local cursor
    }
    __syncthreads();
    // scatter: this block is the ONLY writer of its runs
#pragma unroll
    for (int j = 0; j < CHUNK / 256; j++) {
        int e = e0 + j * 256 + t;
        if (e < E) {
            int d = dst[e];
            int b = d >> BSH;
            int off = atomicAdd(&cnt[b], 1);
            stage[base[b] + off] =
                (unsigned int)src[e] | ((unsigned int)(d & ((1 << BSH) - 1)) << SRCBITS);
        }
    }
}

// ---------------- per-bucket CSR fill (512 nodes/bucket) ----------------
__global__ __launch_bounds__(256) void kP2(const unsigned int* __restrict__ stage,
                                           const int* __restrict__ bstart,
                                           int* __restrict__ rowptr,
                                           float* __restrict__ dinv,
                                           int* __restrict__ col, int Nn) {
    __shared__ int deg[512];
    __shared__ int cur[512];
    __shared__ int sums[256];
    int b = blockIdx.x;
    int t = threadIdx.x;
    int bs = bstart[b], be = bstart[b + 1];
    deg[t] = 0; deg[t + 256] = 0;
    __syncthreads();
    for (int i = bs + t; i < be; i += 256)
        atomicAdd(&deg[stage[i] >> SRCBITS], 1);
    __syncthreads();
    // scan 512 via 256 threads (2 elems each)
    int d0 = deg[2 * t], d1 = deg[2 * t + 1];
    int s = d0 + d1;
    sums[t] = s;
    __syncthreads();
    for (int off = 1; off < 256; off <<= 1) {
        int v = (t >= off) ? sums[t - off] : 0;
        __syncthreads();
        sums[t] += v;
        __syncthreads();
    }
    int pref = sums[t] - s;            // exclusive prefix of pair
    int n0 = b << BSH;
    int n = n0 + 2 * t;
    if (n < Nn) {
        rowptr[n] = bs + pref;
        dinv[n] = rsqrtf((float)(d0 + 1));
    }
    if (n + 1 < Nn) {
        rowptr[n + 1] = bs + pref + d0;
        dinv[n + 1] = rsqrtf((float)(d1 + 1));
    }
    cur[2 * t] = pref;
    cur[2 * t + 1] = pref + d0;
    __syncthreads();
    for (int i = bs + t; i < be; i += 256) {
        unsigned int u = stage[i];
        int dn = u >> SRCBITS;
        int pos = bs + atomicAdd(&cur[dn], 1);
        col[pos] = (int)(u & SRCMASK);
    }
}

// ---------------- GEMM1: [M,256] @ [256,128], scale rows by dinv ----------------
// As stored k-major [32][132] so the per-kk A-fragment is 2x ds_read_b128.
__global__ __launch_bounds__(256) void k_gemm1(const float* __restrict__ X,
                                               const float* __restrict__ W,
                                               const float* __restrict__ dinv,
                                               float* __restrict__ H, int M) {
    __shared__ float As[32][132];   // k-major
    __shared__ float Bs[32][128];
    int t = threadIdx.x;
    int tx = t & 15, ty = t >> 4;
    int row0 = blockIdx.x * 128;

    float acc[8][8];
#pragma unroll
    for (int i = 0; i < 8; i++)
#pragma unroll
        for (int j = 0; j < 8; j++) acc[i][j] = 0.f;

    int arow = t >> 3;          // 0..31
    int acol = (t & 7) * 4;     // 0..28 (k within tile)
    int brow = t >> 5;          // 0..7
    int bcol = (t & 31) * 4;    // 0..124

    for (int k0 = 0; k0 < NFEAT; k0 += 32) {
#pragma unroll
        for (int p = 0; p < 4; p++) {
            int r = p * 32 + arow;
            int gr = row0 + r;
            float4 v = make_float4(0.f, 0.f, 0.f, 0.f);
            if (gr < M) v = *(const float4*)&X[(size_t)gr * NFEAT + k0 + acol];
            As[acol + 0][r] = v.x; As[acol + 1][r] = v.y;
            As[acol + 2][r] = v.z; As[acol + 3][r] = v.w;
        }
#pragma unroll
        for (int p = 0; p < 4; p++) {
            int kr = p * 8 + brow;
            *(float4*)&Bs[kr][bcol] = *(const float4*)&W[(size_t)(k0 + kr) * HID + bcol];
        }
        __syncthreads();
#pragma unroll
        for (int kk = 0; kk < 32; kk++) {
            float a[8], b[8];
            *(float4*)&a[0] = *(const float4*)&As[kk][ty * 8];
            *(float4*)&a[4] = *(const float4*)&As[kk][ty * 8 + 4];
            *(float4*)&b[0] = *(const float4*)&Bs[kk][tx * 4];
            *(float4*)&b[4] = *(const float4*)&Bs[kk][64 + tx * 4];
#pragma unroll
            for (int i = 0; i < 8; i++)
#pragma unroll
                for (int j = 0; j < 8; j++) acc[i][j] += a[i] * b[j];
        }
        __syncthreads();
    }
#pragma unroll
    for (int i = 0; i < 8; i++) {
        int gr = row0 + ty * 8 + i;
        if (gr < M) {
            float dv = dinv[gr];
            float4 v0 = make_float4(acc[i][0] * dv, acc[i][1] * dv, acc[i][2] * dv, acc[i][3] * dv);
            float4 v1 = make_float4(acc[i][4] * dv, acc[i][5] * dv, acc[i][6] * dv, acc[i][7] * dv);
            *(float4*)&H[(size_t)gr * HID + tx * 4] = v0;
            *(float4*)&H[(size_t)gr * HID + 64 + tx * 4] = v1;
        }
    }
}

// ---------------- aggregation layer1 ----------------
// wave per node. g = lane>>5 selects edge slot (2 rows/iter), c = lane&31 is a
// float4 chunk (32 lanes x 16B = full 512B row). unroll 4 -> 8 rows in flight.
__global__ __launch_bounds__(256) void k_agg1(const float* __restrict__ H1,
                                              const int* __restrict__ rowptr,
                                              const int* __restrict__ col,
                                              const float* __restrict__ dinv,
                                              const float* __restrict__ b1,
                                              float* __restrict__ out, int N) {
    int node = blockIdx.x * 4 + (threadIdx.x >> 6);
    if (node >= N) return;
    int lane = threadIdx.x & 63;
    int g = lane >> 5;          // 0..1
    int c = lane & 31;          // float4 index within row

    float4 acc = make_float4(0.f, 0.f, 0.f, 0.f);
    if (g == 0)  // self loop (prescaled) counted once
        acc = *(const float4*)&H1[(size_t)node * HID + c * 4];

    int e = rowptr[node], e1 = rowptr[node + 1];
    for (; e + 7 < e1; e += 8) {
        int s0 = col[e + g];
        int s1 = col[e + 2 + g];
        int s2 = col[e + 4 + g];
        int s3 = col[e + 6 + g];
        float4 v0 = *(const float4*)&H1[(size_t)s0 * HID + c * 4];
        float4 v1 = *(const float4*)&H1[(size_t)s1 * HID + c * 4];
        float4 v2 = *(const float4*)&H1[(size_t)s2 * HID + c * 4];
        float4 v3 = *(const float4*)&H1[(size_t)s3 * HID + c * 4];
        acc.x += (v0.x + v1.x) + (v2.x + v3.x);
        acc.y += (v0.y + v1.y) + (v2.y + v3.y);
        acc.z += (v0.z + v1.z) + (v2.z + v3.z);
        acc.w += (v0.w + v1.w) + (v2.w + v3.w);
    }
    for (; e + 1 < e1; e += 2) {
        int s = col[e + g];
        float4 v = *(const float4*)&H1[(size_t)s * HID + c * 4];
        acc.x += v.x; acc.y += v.y; acc.z += v.z; acc.w += v.w;
    }
    if (e < e1 && g == 0) {     // odd remaining edge
        int s = col[e];
        float4 v = *(const float4*)&H1[(size_t)s * HID + c * 4];
        acc.x += v.x; acc.y += v.y; acc.z += v.z; acc.w += v.w;
    }
    // combine the two edge slots
    acc.x += __shfl_xor(acc.x, 32);
    acc.y += __shfl_xor(acc.y, 32);
    acc.z += __shfl_xor(acc.z, 32);
    acc.w += __shfl_xor(acc.w, 32);

    if (g == 0) {
        float dv = dinv[node];
        float4 bb = *(const float4*)&b1[c * 4];
        float4 r;
        r.x = fmaxf(acc.x * dv + bb.x, 0.f);
        r.y = fmaxf(acc.y * dv + bb.y, 0.f);
        r.z = fmaxf(acc.z * dv + bb.z, 0.f);
        r.w = fmaxf(acc.w * dv + bb.w, 0.f);
        *(float4*)&out[(size_t)node * HID + c * 4] = r;
    }
}

// ---------------- GEMM2: [M,128] @ [128,40], W2 fully in LDS ----------------
__global__ __launch_bounds__(256) void k_gemm2(const float* __restrict__ A,
                                               const float* __restrict__ W,
                                               const float* __restrict__ dinv,
                                               float* __restrict__ H, int M) {
    __shared__ float As[64][129];          // pad: conflict-free
    __shared__ float Ws[HID * NCLS];       // 20 KB
    int t = threadIdx.x;
    for (int idx = t; idx < HID * NCLS; idx += 256) Ws[idx] = W[idx];

    int row0 = blockIdx.x * 64;
#pragma unroll
    for (int p = 0; p < 8; p++) {
        int flat = (p * 256 + t) * 4;      // 64*128 floats
        int r = flat >> 7;                 // /128
        int c = flat & 127;
        int gr = row0 + r;
        float4 v = make_float4(0.f, 0.f, 0.f, 0.f);
        if (gr < M) v = *(const float4*)&A[(size_t)gr * HID + c];
        As[r][c + 0] = v.x; As[r][c + 1] = v.y; As[r][c + 2] = v.z; As[r][c + 3] = v.w;
    }
    __syncthreads();

    int r = t >> 2;            // 0..63
    int cg = (t & 3) * 10;     // col group base
    float acc[10];
#pragma unroll
    for (int j = 0; j < 10; j++) acc[j] = 0.f;
    for (int k = 0; k < HID; k++) {
        float a = As[r][k];
        const float* wrow = &Ws[k * NCLS + cg];
#pragma unroll
        for (int j = 0; j < 10; j++) acc[j] += a * wrow[j];
    }
    int gr = row0 + r;
    if (gr < M) {
        float dv = dinv[gr];
#pragma unroll
        for (int j = 0; j < 10; j++) H[(size_t)gr * NCLS + cg + j] = acc[j] * dv;
    }
}

// ---------------- aggregation layer2 ----------------
// wave per node. g = lane/10 selects edge slot (6 rows/iter), c = lane%10 is a
// float4 chunk (10 lanes x 16B = full 160B row). unroll 2 -> 12 rows in flight.
__global__ __launch_bounds__(256) void k_agg2(const float* __restrict__ H2,
                                              const int* __restrict__ rowptr,
                                              const int* __restrict__ col,
                                              const float* __restrict__ dinv,
                                              const float* __restrict__ b2,
                                              float* __restrict__ out, int N) {
    int node = blockIdx.x * 4 + (threadIdx.x >> 6);
    if (node >= N) return;
    int lane = threadIdx.x & 63;
    int g = lane / 10;          // 0..6 (g==6 -> lanes 60..63 idle)
    int c = lane % 10;          // float4 index within 40-float row
    bool active = g < 6;

    float4 acc = make_float4(0.f, 0.f, 0.f, 0.f);
    if (g == 0)  // self loop (prescaled)
        acc = *(const float4*)&H2[(size_t)node * NCLS + c * 4];

    int e = rowptr[node], e1 = rowptr[node + 1];
    for (; e + 11 < e1; e += 12) {
        if (active) {
            int s0 = col[e + g];
            int s1 = col[e + 6 + g];
            float4 v0 = *(const float4*)&H2[(size_t)s0 * NCLS + c * 4];
            float4 v1 = *(const float4*)&H2[(size_t)s1 * NCLS + c * 4];
            acc.x += v0.x + v1.x;
            acc.y += v0.y + v1.y;
            acc.z += v0.z + v1.z;
            acc.w += v0.w + v1.w;
        }
    }
    for (; e < e1; e += 6) {
        int idx = e + g;
        if (active && idx < e1) {
            int s = col[idx];
            float4 v = *(const float4*)&H2[(size_t)s * NCLS + c * 4];
            acc.x += v.x; acc.y += v.y; acc.z += v.z; acc.w += v.w;
        }
    }
    // reduce 6 groups -> group 0. Step 1: g(0,1,2) += g(3,4,5).
    float4 t1, t2;
    t1.x = __shfl(acc.x, lane + 30); t1.y = __shfl(acc.y, lane + 30);
    t1.z = __shfl(acc.z, lane + 30); t1.w = __shfl(acc.w, lane + 30);
    acc.x += t1.x; acc.y += t1.y; acc.z += t1.z; acc.w += t1.w;
    // Step 2: g0 += g1 + g2 (capture both before mutating).
    t1.x = __shfl(acc.x, lane + 10); t1.y = __shfl(acc.y, lane + 10);
    t1.z = __shfl(acc.z, lane + 10); t1.w = __shfl(acc.w, lane + 10);
    t2.x = __shfl(acc.x, lane + 20); t2.y = __shfl(acc.y, lane + 20);
    t2.z = __shfl(acc.z, lane + 20); t2.w = __shfl(acc.w, lane + 20);
    acc.x += t1.x + t2.x; acc.y += t1.y + t2.y;
    acc.z += t1.z + t2.z; acc.w += t1.w + t2.w;

    if (g == 0) {
        float dv = dinv[node];
        float4 bb = *(const float4*)&b2[c * 4];
        float4 r;
        r.x = acc.x * dv + bb.x;
        r.y = acc.y * dv + bb.y;
        r.z = acc.z * dv + bb.z;
        r.w = acc.w * dv + bb.w;
        *(float4*)&out[(size_t)node * NCLS + c * 4] = r;
    }
}

extern "C" void kernel_launch(void* const* d_in, const int* in_sizes, int n_in,
                              void* d_out, int out_size, void* d_ws, size_t ws_size,
                              hipStream_t stream) {
    const float* x  = (const float*)d_in[0];
    const int*   ei = (const int*)d_in[1];   // int32 edge_index
    const float* W1 = (const float*)d_in[2];
    const float* b1 = (const float*)d_in[3];
    const float* W2 = (const float*)d_in[4];
    const float* b2 = (const float*)d_in[5];
    float* out = (float*)d_out;

    const int N = in_sizes[0] / NFEAT;       // 100000
    const int E = in_sizes[1] / 2;           // 1600000
    const int NB = (N + (1 << BSH) - 1) >> BSH;  // 196 coarse buckets
    const int* src = ei;
    const int* dst = ei + E;

    // workspace layout (256B aligned)
    char* ws = (char*)d_ws;
    size_t off = 0;
    auto alloc = [&](size_t bytes) { size_t cur = off; off = (off + bytes + 255) & ~255ULL; return cur; };
    int*   rowptr  = (int*)(ws + alloc(((size_t)N + 1) * 4));
    float* dinv    = (float*)(ws + alloc((size_t)N * 4));
    int*   bcount  = (int*)(ws + alloc(((size_t)NB + 1) * 4));
    int*   bstart  = (int*)(ws + alloc(((size_t)NB + 1) * 4));
    int*   bcursor = (int*)(ws + alloc(((size_t)NB + 1) * 4));
    int*   colv    = (int*)(ws + alloc((size_t)E * 4));
    float* h1s     = (float*)(ws + alloc((size_t)N * HID * 4));
    float* hrelu   = (float*)(ws + alloc((size_t)N * HID * 4));
    float* h2s     = h1s;                          // reuse: h1s dead after k_agg1
    unsigned int* stage = (unsigned int*)hrelu;    // reuse: stage dead before k_agg1 writes hrelu

    hipMemsetAsync(bcount, 0, ((size_t)NB + 1) * 4, stream);

    kA_bhist<<<128, 256, 0, stream>>>(dst, bcount, E, NB);
    kB_bscan<<<1, 256, 0, stream>>>(bcount, bstart, bcursor, rowptr, NB, N, E);
    kP1<<<(E + CHUNK - 1) / CHUNK, 256, 0, stream>>>(src, dst, bcursor, stage, E, NB);
    kP2<<<NB, 256, 0, stream>>>(stage, bstart, rowptr, dinv, colv, N);

    k_gemm1<<<(N + 127) / 128, 256, 0, stream>>>(x, W1, dinv, h1s, N);
    k_agg1<<<(N + 3) / 4, 256, 0, stream>>>(h1s, rowptr, colv, dinv, b1, hrelu, N);
    k_gemm2<<<(N + 63) / 64, 256, 0, stream>>>(hrelu, W2, dinv, h2s, N);
    k_agg2<<<(N + 3) / 4, 256, 0, stream>>>(h2s, rowptr, colv, dinv, b2, out, N);
}